// Round 4
// baseline (258.651 us; speedup 1.0000x reference)
//
#include <hip/hip_runtime.h>

// GRU B=32,T=50,N=1024,C=128,H=64 via fp16 MFMA 32x32x16, fp32 accum.
// 256 blocks x 8 waves (512 thr); waves pair up: each PAIR owns one group of 32
// sequences; wave jj in {0,1} computes hidden cols jj*32..jj*32+31 (gate tiles
// jj, 2+jj, 4+jj). -> 2048 waves = 2 waves/SIMD (TLP hides MFMA dep latency &
// transcendentals). Wih+Whh fp16 in LDS (swizzled); x staged cooperatively per
// group into LDS f16 once; h shared via per-group LDS tile, 2 barriers/step.

typedef _Float16 half8 __attribute__((ext_vector_type(8)));
typedef float f32x16 __attribute__((ext_vector_type(16)));

constexpr int T_ = 50, N_ = 1024, C_ = 128, H_ = 64;
constexpr uint32_t WIH_OFF = 0;       // 192 rows x 256B (128 f16)   = 49152
constexpr uint32_t WHH_OFF = 49152;   // 192 rows x 128B ( 64 f16)   = 24576
constexpr uint32_t XT_OFF  = 73728;   // 4 grp x 32 rows x 256B f16  = 32768
constexpr uint32_t HT_OFF  = 106496;  // 4 grp x 32 rows x 128B f16  = 16384
constexpr int LDS_BYTES = 122880;     // 120 KB -> 1 block/CU

__global__ void prep_weights(const float* __restrict__ Wih, const float* __restrict__ Whh,
                             _Float16* __restrict__ w16) {
  int i = blockIdx.x * 256 + threadIdx.x;
  if (i < 192 * 128) w16[i] = (_Float16)Wih[i];
  if (i < 192 * 64)  w16[24576 + i] = (_Float16)Whh[i];
}

__device__ __forceinline__ float sigm(float x) {
  return __builtin_amdgcn_rcpf(1.f + __expf(-x));
}

__global__ __launch_bounds__(512, 2) void gru_pair(
    const float* __restrict__ x, const _Float16* __restrict__ w16,
    const float* __restrict__ bih, const float* __restrict__ bhh,
    float* __restrict__ out)
{
  __shared__ __align__(16) char lds[LDS_BYTES];
  const int tid = threadIdx.x;

  // ---- stage weights into LDS (swizzled); zero h tiles ----
  {
    const _Float16* wih = w16;
    const _Float16* whh = w16 + 24576;
#pragma unroll
    for (int rep = 0; rep < 6; ++rep) {            // Wih: 3072 16B chunks
      int i = tid + rep * 512;
      int row = i >> 4, gr = i & 15;
      uint32_t byte = (uint32_t)row * 256 + (uint32_t)((gr ^ (row & 15)) << 4);
      *(half8*)(lds + WIH_OFF + byte) = *(const half8*)(wih + i * 8);
    }
#pragma unroll
    for (int rep = 0; rep < 3; ++rep) {            // Whh: 1536 16B chunks
      int i = tid + rep * 512;
      int row = i >> 3, gr = i & 7;
      uint32_t byte = (uint32_t)row * 128 + (uint32_t)((gr ^ (row & 7)) << 4);
      *(half8*)(lds + WHH_OFF + byte) = *(const half8*)(whh + i * 8);
    }
    half8 zz = {};
    *(half8*)(lds + HT_OFF + tid * 32)      = zz;  // 512*32 = 16384 B
    *(half8*)(lds + HT_OFF + tid * 32 + 16) = zz;
  }
  __syncthreads();

  const int wv = tid >> 6, lane = tid & 63;
  const int c32 = lane & 31, hf = lane >> 5;
  const int gl = wv >> 1, jj = wv & 1;             // group-in-block, col-half role
  const int seq0 = blockIdx.x * 128 + gl * 32;
  const int b = seq0 >> 10, n0 = seq0 & (N_ - 1);
  const uint32_t xt = XT_OFF + (uint32_t)gl * 8192;
  const uint32_t ht = HT_OFF + (uint32_t)gl * 4096;
  const int j = jj * 32 + c32;                     // this lane's hidden col
  const int sw15 = c32 & 15, sw7 = c32 & 7;

  // per-lane biases
  const float br  = bih[j] + bhh[j];
  const float bz  = bih[64 + j] + bhh[64 + j];
  const float bin_ = bih[128 + j];
  const float bhn_ = bhh[128 + j];

  float hr[16];
#pragma unroll
  for (int i = 0; i < 16; ++i) hr[i] = 0.f;

  // cooperative x staging: pair-thread tp in 0..127 -> seq = tp>>2, k0 = (tp&3)*32
  const int tp = jj * 64 + lane;
  const int xseq = tp >> 2, xk0 = (tp & 3) * 32;
  const float* xptr = x + ((size_t)b * T_ * N_ + n0 + xseq) * C_ + xk0;
  const size_t stepstride = (size_t)N_ * C_;

  // B-frag accessors (row = gate*64 + j; swizzle const across gates)
#define WIHB(gate, ks) \
  (*(const half8*)(lds + WIH_OFF + (uint32_t)(((gate) * 64 + j) * 256) + \
                   (uint32_t)((((ks) * 2 + hf) ^ sw15) << 4)))
#define WHHB(gate, ks) \
  (*(const half8*)(lds + WHH_OFF + (uint32_t)(((gate) * 64 + j) * 128) + \
                   (uint32_t)((((ks) * 2 + hf) ^ sw7) << 4)))
#define MFMA(a, bf, acc) __builtin_amdgcn_mfma_f32_32x32x16_f16((a), (bf), (acc), 0, 0, 0)

  // prologue: load x(t=0) : 8 float4 per lane (k0..k0+31 of row xseq)
  float4 raw[8];
#pragma unroll
  for (int l = 0; l < 8; ++l) raw[l] = *(const float4*)(xptr + l * 4);

  for (int t = 0; t < T_; ++t) {
    // (1) convert raw -> f16, write x-tile (granule gj = (tp&3)*4+q, ^ seq&15)
#pragma unroll
    for (int q = 0; q < 4; ++q) {
      const float4 lo = raw[2 * q], hi = raw[2 * q + 1];
      half8 v;
      v[0] = (_Float16)lo.x; v[1] = (_Float16)lo.y;
      v[2] = (_Float16)lo.z; v[3] = (_Float16)lo.w;
      v[4] = (_Float16)hi.x; v[5] = (_Float16)hi.y;
      v[6] = (_Float16)hi.z; v[7] = (_Float16)hi.w;
      const uint32_t gj = (uint32_t)((tp & 3) * 4 + q);
      const uint32_t byte = xt + (uint32_t)xseq * 256 + ((gj ^ (uint32_t)(xseq & 15)) << 4);
      *(half8*)(lds + byte) = v;
    }
    __syncthreads();   // #1: x(t) + h(t-1) writes visible

    // (3) read A-frags: x rows (seq=c32, k slices) and h rows (seq=c32, j slices)
    half8 xa[8];
#pragma unroll
    for (int ks = 0; ks < 8; ++ks)
      xa[ks] = *(const half8*)(lds + xt + (uint32_t)c32 * 256 +
                               (uint32_t)(((ks * 2 + hf) ^ sw15) << 4));
    half8 ha[4];
#pragma unroll
    for (int ks = 0; ks < 4; ++ks)
      ha[ks] = *(const half8*)(lds + ht + (uint32_t)c32 * 128 +
                               (uint32_t)(((ks * 2 + hf) ^ sw7) << 4));
    __syncthreads();   // #2: all reads done before anyone overwrites x/h

    f32x16 aR = {}, aZ = {}, aN = {}, aH = {};

    // (5) x-part: K=128, 3-way interleaved accumulator chains
#pragma unroll
    for (int ks = 0; ks < 8; ++ks) {
      aR = MFMA(xa[ks], WIHB(0, ks), aR);
      aZ = MFMA(xa[ks], WIHB(1, ks), aZ);
      aN = MFMA(xa[ks], WIHB(2, ks), aN);
    }

    // (6) prefetch x(t+1); consumed at (1) of t+1, covered by h-part + gates
    {
      const int tn = (t + 1 < T_) ? t + 1 : T_ - 1;
      const float* xp = xptr + (size_t)tn * stepstride;
#pragma unroll
      for (int l = 0; l < 8; ++l) raw[l] = *(const float4*)(xp + l * 4);
    }

    // (7) h-part: K=64
#pragma unroll
    for (int ks = 0; ks < 4; ++ks) {
      aR = MFMA(ha[ks], WHHB(0, ks), aR);
      aZ = MFMA(ha[ks], WHHB(1, ks), aZ);
      aH = MFMA(ha[ks], WHHB(2, ks), aH);
    }

    // (8) gates: D row(seq) = (rg&3)+8*(rg>>2)+4*hf, col = j (lane-local)
#pragma unroll
    for (int rg = 0; rg < 16; ++rg) {
      const int seq = (rg & 3) + 8 * (rg >> 2) + 4 * hf;
      const float r = sigm(aR[rg] + br);
      const float z = sigm(aZ[rg] + bz);
      const float np = aN[rg] + bin_ + r * (aH[rg] + bhn_);
      const float nn = 1.f - 2.f * __builtin_amdgcn_rcpf(__expf(2.f * np) + 1.f);
      const float hn = (1.f - z) * nn + z * hr[rg];
      hr[rg] = hn;
      const uint32_t gj = (uint32_t)(jj * 4 + (c32 >> 3));
      const uint32_t byte = ht + (uint32_t)seq * 128 +
                            ((gj ^ (uint32_t)(seq & 7)) << 4) + (uint32_t)((c32 & 7) * 2);
      *(_Float16*)(lds + byte) = (_Float16)hn;
    }
  }

  // ---- store final h (fp32 carry) ----
#pragma unroll
  for (int rg = 0; rg < 16; ++rg) {
    const int seq = (rg & 3) + 8 * (rg >> 2) + 4 * hf;
    out[(size_t)(seq0 + seq) * H_ + j] = hr[rg];
  }
#undef WIHB
#undef WHHB
#undef MFMA
}

extern "C" void kernel_launch(void* const* d_in, const int* in_sizes, int n_in,
                              void* d_out, int out_size, void* d_ws, size_t ws_size,
                              hipStream_t stream) {
  const float* chars = (const float*)d_in[0];
  const float* Wih   = (const float*)d_in[1];
  const float* Whh   = (const float*)d_in[2];
  const float* bih   = (const float*)d_in[3];
  const float* bhh   = (const float*)d_in[4];

  _Float16* w16 = (_Float16*)d_ws;   // 36864 f16 = 73728 B

  prep_weights<<<96, 256, 0, stream>>>(Wih, Whh, w16);
  gru_pair<<<256, 512, 0, stream>>>(chars, w16, bih, bhh, (float*)d_out);
}